// Round 1
// 219.720 us; speedup vs baseline: 1.0300x; 1.0300x over previous
//
#include <hip/hip_runtime.h>
#include <math.h>

// Problem constants
constexpr int Dm   = 1024;
constexpr int NH   = 16;
constexpr int HD   = 64;
constexpr int Bb   = 2;
constexpr int Tt   = 2048;
constexpr int MTOT = Bb * Tt;   // 4096
#define EPSF 1e-6f

typedef __attribute__((ext_vector_type(8))) short short8;   // 8 x bf16
typedef __attribute__((ext_vector_type(4))) float f32x4;    // MFMA acc
typedef __attribute__((ext_vector_type(2))) float f32x2;    // packed fp32 pair

__device__ __forceinline__ ushort f2bf(float f) {
    union { float f; unsigned u; } v; v.f = f;
    unsigned r = (v.u + 0x7FFFu + ((v.u >> 16) & 1u)) >> 16;   // RNE
    return (ushort)r;
}

// packed fp32 pair -> one u32 holding 2 bf16 (RNE), low = first arg
__device__ __forceinline__ unsigned cvt_pk_bf16(float lo, float hi) {
    unsigned r;
    asm("v_cvt_pk_bf16_f32 %0, %1, %2" : "=v"(r) : "v"(lo), "v"(hi));
    return r;
}

// async global->LDS, 16B/lane. PROVEN in gemm_core; CONVICTED in attn (R4-R6
// fails, R7 bisect) — do not use outside gemm-style kernels.
__device__ __forceinline__ void gload16(const void* g, void* l) {
    __builtin_amdgcn_global_load_lds(
        (const __attribute__((address_space(1))) unsigned int*)g,
        (__attribute__((address_space(3))) unsigned int*)l,
        16, 0, 0);
}

// ---------------------------------------------------------------------------
// fp32 -> bf16 for all five tensors in one launch.
// ---------------------------------------------------------------------------
__global__ __launch_bounds__(256)
void cvt_all(const float* __restrict__ x,  const float* __restrict__ wq,
             const float* __restrict__ wk, const float* __restrict__ wv,
             const float* __restrict__ wo,
             ushort* __restrict__ xb,  ushort* __restrict__ wqb,
             ushort* __restrict__ wkb, ushort* __restrict__ wvb,
             ushort* __restrict__ wob) {
    int i = blockIdx.x * 256 + threadIdx.x;   // float4 index
    const float* src; ushort* dst; int off;
    if (i < 1048576)      { src = x;  dst = xb;  off = i; }
    else if (i < 1310720) { src = wq; dst = wqb; off = i - 1048576; }
    else if (i < 1572864) { src = wk; dst = wkb; off = i - 1310720; }
    else if (i < 1835008) { src = wv; dst = wvb; off = i - 1572864; }
    else                  { src = wo; dst = wob; off = i - 1835008; }
    const float4 v = ((const float4*)src)[off];
    ushort4 o;
    o.x = f2bf(v.x); o.y = f2bf(v.y); o.z = f2bf(v.z); o.w = f2bf(v.w);
    ((ushort4*)dst)[off] = o;
}

// ---------------------------------------------------------------------------
// 128x128x(BK=64) bf16 MFMA GEMM core (m97-style, XOR-swizzled LDS).
// PROVEN R3/R7/R8/R9. mode: 0 = plain, 1 = per-64col L2 norm (Q/K),
// 2 = V transposed per head into Vt[b,h,d,t] via packed uint2 stores.
// ---------------------------------------------------------------------------
template<bool OUTF32>
__device__ __forceinline__
void gemm_core(const ushort* __restrict__ A, const ushort* __restrict__ W,
               const float* __restrict__ bias, void* __restrict__ out,
               int m0, int n0, int N, int K, int mode) {
    __shared__ ushort As[128 * 64];
    __shared__ ushort Bs[128 * 64];
    const int tid  = threadIdx.x;
    const int wave = tid >> 6, lane = tid & 63;
    const int quad = lane >> 4, l15 = lane & 15;
    const int wr = wave >> 1, wc = wave & 1;
    const int lr = lane >> 3;
    const int sc = (lane & 7) ^ lr;

    f32x4 acc[4][4] = {};
    const ushort* Ab = A + (size_t)(m0 + lr) * K + sc * 8;
    const ushort* Wb = W + (size_t)(n0 + lr) * K + sc * 8;

    for (int k0 = 0; k0 < K; k0 += 64) {
        #pragma unroll
        for (int i = 0; i < 4; i++) {
            const int rows8 = (wave * 4 + i) * 8;
            gload16(Ab + (size_t)rows8 * K + k0, &As[rows8 * 64]);
            gload16(Wb + (size_t)rows8 * K + k0, &Bs[rows8 * 64]);
        }
        __syncthreads();
        #pragma unroll
        for (int kh = 0; kh < 2; kh++) {
            short8 af[4];
            #pragma unroll
            for (int mi = 0; mi < 4; mi++) {
                const int row = wr * 64 + mi * 16 + l15;
                af[mi] = *(const short8*)&As[row * 64 + (((kh * 4 + quad) ^ (row & 7)) * 8)];
            }
            #pragma unroll
            for (int nj = 0; nj < 4; nj++) {
                const int row = wc * 64 + nj * 16 + l15;
                const short8 bf = *(const short8*)&Bs[row * 64 + (((kh * 4 + quad) ^ (row & 7)) * 8)];
                #pragma unroll
                for (int mi = 0; mi < 4; mi++)
                    acc[mi][nj] = __builtin_amdgcn_mfma_f32_16x16x32_bf16(af[mi], bf, acc[mi][nj], 0, 0, 0);
            }
        }
        __syncthreads();
    }

    if (!OUTF32 && mode == 2) {
        #pragma unroll
        for (int mi = 0; mi < 4; mi++) {
            const int t  = m0 + wr * 64 + mi * 16 + quad * 4;
            const int bb = t >> 11, tl = t & 2047;
            #pragma unroll
            for (int nj = 0; nj < 4; nj++) {
                const int n = n0 + wc * 64 + nj * 16 + l15;
                const int hh = n >> 6, dd = n & 63;
                uint2 pk;
                pk.x = (unsigned)f2bf(acc[mi][nj][0]) | ((unsigned)f2bf(acc[mi][nj][1]) << 16);
                pk.y = (unsigned)f2bf(acc[mi][nj][2]) | ((unsigned)f2bf(acc[mi][nj][3]) << 16);
                *(uint2*)&((ushort*)out)[(size_t)((bb * NH + hh) * HD + dd) * Tt + tl] = pk;
            }
        }
        return;
    }

    #pragma unroll
    for (int mi = 0; mi < 4; mi++) {
        float inv[4] = {1.f, 1.f, 1.f, 1.f};
        if (!OUTF32 && mode == 1) {
            #pragma unroll
            for (int r = 0; r < 4; r++) {
                float ss = 0.f;
                #pragma unroll
                for (int nj = 0; nj < 4; nj++) ss += acc[mi][nj][r] * acc[mi][nj][r];
                ss += __shfl_xor(ss, 1); ss += __shfl_xor(ss, 2);
                ss += __shfl_xor(ss, 4); ss += __shfl_xor(ss, 8);
                inv[r] = 1.f / fmaxf(sqrtf(ss), EPSF);
            }
        }
        #pragma unroll
        for (int nj = 0; nj < 4; nj++)
            #pragma unroll
            for (int r = 0; r < 4; r++) {
                const int row = m0 + wr * 64 + mi * 16 + quad * 4 + r;
                const int col = n0 + wc * 64 + nj * 16 + l15;
                if (OUTF32)
                    ((float*)out)[(size_t)row * N + col] = acc[mi][nj][r] + bias[col];
                else
                    ((ushort*)out)[(size_t)row * N + col] = f2bf(acc[mi][nj][r] * inv[r]);
            }
    }
}

// Q/K: normed bf16 out; V: direct-transposed into vtb.
__global__ __launch_bounds__(256)
void qkv_gemm(const ushort* __restrict__ xb,
              const ushort* __restrict__ wq, const ushort* __restrict__ wk,
              const ushort* __restrict__ wv,
              ushort* __restrict__ qb, ushort* __restrict__ kb,
              ushort* __restrict__ vtb) {
    const int ny = blockIdx.y, sel = ny >> 3;
    const ushort* W = (sel == 0) ? wq : (sel == 1) ? wk : wv;
    ushort* out     = (sel == 0) ? qb : (sel == 1) ? kb : vtb;
    gemm_core<false>(xb, W, nullptr, out, blockIdx.x * 128, (ny & 7) * 128,
                     Dm, Dm, (sel < 2) ? 1 : 2);
}

// ---------------------------------------------------------------------------
// Output projection, 64x128 tile (grid 64x8 = 512 blocks = 2/CU vs the old
// 128x128's 256 blocks = 1/CU — co-residency for barrier overlap).
// Same staging/swizzle vocabulary as gemm_core; wave = (m-half 32) x (n-half 64).
// ---------------------------------------------------------------------------
__global__ __launch_bounds__(256)
void out_gemm(const ushort* __restrict__ A, const ushort* __restrict__ W,
              const float* __restrict__ bias, float* __restrict__ out) {
    __shared__ ushort As[64 * 64];
    __shared__ ushort Bs[128 * 64];
    const int tid  = threadIdx.x;
    const int wave = tid >> 6, lane = tid & 63;
    const int quad = lane >> 4, l15 = lane & 15;
    const int wm = wave & 1, wn = wave >> 1;
    const int lr = lane >> 3;
    const int sc = (lane & 7) ^ lr;
    const int m0 = blockIdx.x * 64, n0 = blockIdx.y * 128;
    const int K = Dm, N = Dm;

    f32x4 acc[2][4] = {};
    const ushort* Ab = A + (size_t)(m0 + lr) * K + sc * 8;
    const ushort* Wb = W + (size_t)(n0 + lr) * K + sc * 8;

    for (int k0 = 0; k0 < K; k0 += 64) {
        #pragma unroll
        for (int i = 0; i < 2; i++) {            // A: 8 groups, 2 per wave
            const int rows8 = (wave * 2 + i) * 8;
            gload16(Ab + (size_t)rows8 * K + k0, &As[rows8 * 64]);
        }
        #pragma unroll
        for (int i = 0; i < 4; i++) {            // B: 16 groups, 4 per wave
            const int rows8 = (wave * 4 + i) * 8;
            gload16(Wb + (size_t)rows8 * K + k0, &Bs[rows8 * 64]);
        }
        __syncthreads();
        #pragma unroll
        for (int kh = 0; kh < 2; kh++) {
            short8 af[2];
            #pragma unroll
            for (int mi = 0; mi < 2; mi++) {
                const int row = wm * 32 + mi * 16 + l15;
                af[mi] = *(const short8*)&As[row * 64 + (((kh * 4 + quad) ^ (row & 7)) * 8)];
            }
            #pragma unroll
            for (int nj = 0; nj < 4; nj++) {
                const int row = wn * 64 + nj * 16 + l15;
                const short8 bf = *(const short8*)&Bs[row * 64 + (((kh * 4 + quad) ^ (row & 7)) * 8)];
                #pragma unroll
                for (int mi = 0; mi < 2; mi++)
                    acc[mi][nj] = __builtin_amdgcn_mfma_f32_16x16x32_bf16(af[mi], bf, acc[mi][nj], 0, 0, 0);
            }
        }
        __syncthreads();
    }
    #pragma unroll
    for (int mi = 0; mi < 2; mi++)
        #pragma unroll
        for (int nj = 0; nj < 4; nj++)
            #pragma unroll
            for (int r = 0; r < 4; r++) {
                const int row = m0 + wm * 32 + mi * 16 + quad * 4 + r;
                const int col = n0 + wn * 64 + nj * 16 + l15;
                out[(size_t)row * N + col] = acc[mi][nj][r] + bias[col];
            }
}

// ---------------------------------------------------------------------------
// Fused angular attention, R11: swapped-operand layout — compute S^T=mfma(K,Q)
// so each lane owns W^T[k=16jk+quad*4+r][q=l15]; transform in fp32 registers
// (same sqrt-factored cubic as R10); then build the PV B-operand W^T fragment
// IN REGISTERS via v_cvt_pk_bf16_f32 + v_permlane32_swap + v_permlane16_swap
// (derivation: target lane quad Q needs k=8Q..8Q+7; 32-swap then 16-swap of
// the (jk,jk+1) packed pairs lands words {r0,r2}/{r1,r3} exactly).
// PV becomes O^T = mfma(V^T, W^T) — Vs reads are the identical ds_read_b128s.
// This deletes the Ws LDS buffer, 32 f2bf + 16 ds_write_b16 + addr math per
// wave-iter, one of the two __syncthreads per k-tile, and the Ws re-reads.
// ---------------------------------------------------------------------------
__global__ __launch_bounds__(256)
void attn_kernel(const ushort* __restrict__ Qb, const ushort* __restrict__ Kb,
                 const ushort* __restrict__ Vtb, ushort* __restrict__ Ob) {
    __shared__ ushort Ks[2][64 * 64];
    __shared__ ushort Vs[2][64 * 64];
    const int tid  = threadIdx.x;
    const int wave = tid >> 6, lane = tid & 63;
    const int quad = lane >> 4, l15 = lane & 15;
    const int t0 = blockIdx.x * 64, h = blockIdx.y, b = blockIdx.z;

    // Q row for this lane (used as the MFMA *B* operand now: col = q = l15)
    const size_t qrow = (size_t)(b * Tt + t0 + 16 * wave + l15) * Dm + h * HD;
    const short8 qf0 = *(const short8*)&Qb[qrow + quad * 8];
    const short8 qf1 = *(const short8*)&Qb[qrow + 32 + quad * 8];

    const size_t kbase  = (size_t)(b * Tt) * Dm + h * HD;
    const size_t vtbase = (size_t)((b * NH + h) * HD) * Tt;
    const int r0 = tid >> 3, ch0 = tid & 7;
    const ushort* kg = Kb  + kbase  + (size_t)r0 * Dm + ch0 * 8;
    const ushort* vg = Vtb + vtbase + (size_t)r0 * Tt + ch0 * 8;
    const int lsw0 = r0 * 64 + ((ch0 ^ (r0 & 7)) * 8);
    const int lsw1 = (r0 + 32) * 64 + ((ch0 ^ (r0 & 7)) * 8);

    f32x4 oacc[4] = {};          // O^T: oacc[jd][r] = O^T[d=16jd+quad*4+r][q=l15]
    f32x2 denp = {0.f, 0.f};     // per-lane denominator (q = l15 fixed)

    // h(t) cubic: nodes t=0,0.5,1,1.5
    const f32x2 h3 = { 0.011180f,  0.011180f};
    const f32x2 h2 = {-0.002070f, -0.002070f};
    const f32x2 h1 = { 0.040732f,  0.040732f};
    const f32x2 h0 = { 0.450158f,  0.450158f};

    // prologue: stage tile 0 into buffer 0
    short8 pk0 = *(const short8*)kg;
    short8 pk1 = *(const short8*)(kg + (size_t)32 * Dm);
    short8 pv0 = *(const short8*)vg;
    short8 pv1 = *(const short8*)(vg + (size_t)32 * Tt);
    *(short8*)&Ks[0][lsw0] = pk0;  *(short8*)&Ks[0][lsw1] = pk1;
    *(short8*)&Vs[0][lsw0] = pv0;  *(short8*)&Vs[0][lsw1] = pv1;
    __syncthreads();

    const ushort* kgp = kg + (size_t)64 * Dm;   // next-tile prefetch cursors
    const ushort* vgp = vg + 64;

    for (int i = 0; i < 32; i++) {
        const int p = i & 1;
        if (i < 31) {   // prefetch next tile into registers
            pk0 = *(const short8*)kgp;
            pk1 = *(const short8*)(kgp + (size_t)32 * Dm);
            pv0 = *(const short8*)vgp;
            pv1 = *(const short8*)(vgp + (size_t)32 * Tt);
            kgp += (size_t)64 * Dm;
            vgp += 64;
        }

        // S^T = K Q^T : sfT[jk][r] = S[q=l15][k = 16jk + quad*4 + r]
        f32x4 sfT[4] = {};
        #pragma unroll
        for (int j = 0; j < 4; j++) {
            const int row = 16 * j + l15;
            const short8 kf0 = *(const short8*)&Ks[p][row * 64 + ((quad ^ (row & 7)) * 8)];
            const short8 kf1 = *(const short8*)&Ks[p][row * 64 + (((4 + quad) ^ (row & 7)) * 8)];
            sfT[j] = __builtin_amdgcn_mfma_f32_16x16x32_bf16(kf0, qf0, sfT[j], 0, 0, 0);
            sfT[j] = __builtin_amdgcn_mfma_f32_16x16x32_bf16(kf1, qf1, sfT[j], 0, 0, 0);
        }

        // sqrt-factored angular transform, pair-packed.
        // wA[r] = {w[jk=0][r], w[jk=1][r]},  wB[r] = {w[jk=2][r], w[jk=3][r]}
        f32x2 wA[4], wB[4];
        #pragma unroll
        for (int r = 0; r < 4; r++) {
            f32x2 tA, tB;
            tA.x = __builtin_amdgcn_fmed3f(1.0f - sfT[0][r], 0.001f, 1.999f);
            tA.y = __builtin_amdgcn_fmed3f(1.0f - sfT[1][r], 0.001f, 1.999f);
            tB.x = __builtin_amdgcn_fmed3f(1.0f - sfT[2][r], 0.001f, 1.999f);
            tB.y = __builtin_amdgcn_fmed3f(1.0f - sfT[3][r], 0.001f, 1.999f);
            f32x2 pa = __builtin_elementwise_fma(tA, h3, h2);
            f32x2 pb = __builtin_elementwise_fma(tB, h3, h2);
            pa = __builtin_elementwise_fma(pa, tA, h1);
            pb = __builtin_elementwise_fma(pb, tB, h1);
            pa = __builtin_elementwise_fma(pa, tA, h0);
            pb = __builtin_elementwise_fma(pb, tB, h0);
            f32x2 ra, rb;
            ra.x = __builtin_amdgcn_sqrtf(tA.x); ra.y = __builtin_amdgcn_sqrtf(tA.y);
            rb.x = __builtin_amdgcn_sqrtf(tB.x); rb.y = __builtin_amdgcn_sqrtf(tB.y);
            const f32x2 one2 = {1.0f, 1.0f};
            f32x2 wa = __builtin_elementwise_fma(-ra, pa, one2);   // s = 1 - rt*h
            f32x2 wb = __builtin_elementwise_fma(-rb, pb, one2);
            wa *= wa; wa *= wa; wa *= wa; wa *= wa;                // s^16
            wb *= wb; wb *= wb; wb *= wb; wb *= wb;
            denp += wa; denp += wb;
            wA[r] = wa; wB[r] = wb;
        }

        // Build PV B-operand W^T fragments in registers.
        // k-block 0..31 (jk = 0,1):
        unsigned L0 = cvt_pk_bf16(wA[0].x, wA[1].x);   // {w[0][0], w[0][1]}
        unsigned L1 = cvt_pk_bf16(wA[0].y, wA[1].y);   // {w[1][0], w[1][1]}
        unsigned H0 = cvt_pk_bf16(wA[2].x, wA[3].x);   // {w[0][2], w[0][3]}
        unsigned H1 = cvt_pk_bf16(wA[2].y, wA[3].y);   // {w[1][2], w[1][3]}
        asm("v_permlane32_swap_b32 %0, %1" : "+v"(L0), "+v"(L1));
        asm("v_permlane16_swap_b32 %0, %1" : "+v"(L0), "+v"(L1));
        asm("v_permlane32_swap_b32 %0, %1" : "+v"(H0), "+v"(H1));
        asm("v_permlane16_swap_b32 %0, %1" : "+v"(H0), "+v"(H1));
        int4 bi1; bi1.x = (int)L0; bi1.y = (int)H0; bi1.z = (int)L1; bi1.w = (int)H1;
        const short8 Bf1 = __builtin_bit_cast(short8, bi1);
        // k-block 32..63 (jk = 2,3):
        unsigned L2 = cvt_pk_bf16(wB[0].x, wB[1].x);
        unsigned L3 = cvt_pk_bf16(wB[0].y, wB[1].y);
        unsigned H2 = cvt_pk_bf16(wB[2].x, wB[3].x);
        unsigned H3 = cvt_pk_bf16(wB[2].y, wB[3].y);
        asm("v_permlane32_swap_b32 %0, %1" : "+v"(L2), "+v"(L3));
        asm("v_permlane16_swap_b32 %0, %1" : "+v"(L2), "+v"(L3));
        asm("v_permlane32_swap_b32 %0, %1" : "+v"(H2), "+v"(H3));
        asm("v_permlane16_swap_b32 %0, %1" : "+v"(H2), "+v"(H3));
        int4 bi2; bi2.x = (int)L2; bi2.y = (int)H2; bi2.z = (int)L3; bi2.w = (int)H3;
        const short8 Bf2 = __builtin_bit_cast(short8, bi2);

        // O^T += V^T W^T  (A = V^T fragment: same ds_read pattern as before)
        #pragma unroll
        for (int jd = 0; jd < 4; jd++) {
            const int vrow = 16 * jd + l15;
            const short8 vf0 = *(const short8*)&Vs[p][vrow * 64 + ((quad ^ (vrow & 7)) * 8)];
            const short8 vf1 = *(const short8*)&Vs[p][vrow * 64 + (((4 + quad) ^ (vrow & 7)) * 8)];
            oacc[jd] = __builtin_amdgcn_mfma_f32_16x16x32_bf16(vf0, Bf1, oacc[jd], 0, 0, 0);
            oacc[jd] = __builtin_amdgcn_mfma_f32_16x16x32_bf16(vf1, Bf2, oacc[jd], 0, 0, 0);
        }

        if (i < 31) {
            *(short8*)&Ks[1 - p][lsw0] = pk0;  *(short8*)&Ks[1 - p][lsw1] = pk1;
            *(short8*)&Vs[1 - p][lsw0] = pv0;  *(short8*)&Vs[1 - p][lsw1] = pv1;
        }
        __syncthreads();   // staging visible; Ks/Vs[p] reads done everywhere
    }

    // epilogue: den[q=l15] = lane-sum + cross-quad reduce; rcp is fine
    float d = denp.x + denp.y;
    d += __shfl_xor(d, 16);
    d += __shfl_xor(d, 32);
    const float inv = __builtin_amdgcn_rcpf(d + EPSF);

    // O^T -> O: row t = t0+16*wave+l15 (lane-fixed), cols 16jd+quad*4+r -> 8B stores
    const size_t orow = (size_t)(b * Tt + t0 + 16 * wave + l15) * Dm + h * HD;
    #pragma unroll
    for (int jd = 0; jd < 4; jd++) {
        uint2 pk;
        pk.x = cvt_pk_bf16(oacc[jd][0] * inv, oacc[jd][1] * inv);
        pk.y = cvt_pk_bf16(oacc[jd][2] * inv, oacc[jd][3] * inv);
        *(uint2*)&Ob[orow + 16 * jd + quad * 4] = pk;
    }
}

// ---------------------------------------------------------------------------
extern "C" void kernel_launch(void* const* d_in, const int* in_sizes, int n_in,
                              void* d_out, int out_size, void* d_ws, size_t ws_size,
                              hipStream_t stream) {
    const float* x  = (const float*)d_in[0];
    const float* Wq = (const float*)d_in[1];
    const float* Wk = (const float*)d_in[2];
    const float* Wv = (const float*)d_in[3];
    const float* Wo = (const float*)d_in[4];
    const float* bo = (const float*)d_in[5];
    float* out = (float*)d_out;

    ushort* ws = (ushort*)d_ws;
    const size_t M1 = 1u << 20;
    ushort* xb  = ws;
    ushort* wqb = ws + 4 * M1;
    ushort* wkb = ws + 5 * M1;
    ushort* wvb = ws + 6 * M1;
    ushort* wob = ws + 7 * M1;
    ushort* qb  = ws + 8 * M1;
    ushort* kb  = ws + 12 * M1;
    ushort* vtb = ws + 16 * M1;
    ushort* aob = ws + 20 * M1;

    cvt_all<<<8192, 256, 0, stream>>>(x, Wq, Wk, Wv, Wo, xb, wqb, wkb, wvb, wob);
    qkv_gemm<<<dim3(MTOT / 128, 24), 256, 0, stream>>>(xb, wqb, wkb, wvb, qb, kb, vtb);
    attn_kernel<<<dim3(Tt / 64, NH, Bb), 256, 0, stream>>>(qb, kb, vtb, aob);
    out_gemm<<<dim3(MTOT / 64, Dm / 128), 256, 0, stream>>>(aob, wob, bo, out);
}